// Round 8
// baseline (3027.303 us; speedup 1.0000x reference)
//
#include <hip/hip_runtime.h>
#include <hip/hip_cooperative_groups.h>
#include <cstddef>

namespace cg = cooperative_groups;

// Problem constants (match reference)
constexpr int Bb = 16;
constexpr int Cc = 512;
constexpr int Kk = 32;
constexpr int Nn = 64 * 64;          // 4096 points per batch
constexpr int ITERS = 20;

// Launch geometry: 256 blocks x 1024 threads (16 waves/CU, 4 waves/SIMD).
constexpr int TPB  = 1024;
constexpr int PPB  = 256;            // points per block
constexpr int SUBS = Nn / PPB;       // 16 blocks per batch
constexpr int GRID = Bb * SUBS;      // 256 blocks

// fixed-point scale for deterministic (order-independent) i64 accumulation
constexpr float SCALE_F   = 1099511627776.0f;          // 2^40
constexpr float INVSCALE  = 1.0f / 1099511627776.0f;   // 2^-40

__global__ __launch_bounds__(TPB, 4)
void kmeans_fused(const float* __restrict__ x, const int* __restrict__ idx,
                  float* __restrict__ out,
                  float* __restrict__ invn, float* __restrict__ cent,
                  long long* __restrict__ psums, int* __restrict__ pcounts,
                  int* __restrict__ assign, int* __restrict__ flags)
{
    cg::grid_group gg = cg::this_grid();
    const int t   = threadIdx.x;
    const int bid = blockIdx.x;
    const int b   = bid >> 4;            // bid / SUBS (SUBS = 16)
    const int sub = bid & (SUBS - 1);
    const int base = sub * PPB;

    // ONE 64 KiB static LDS array. Regions (aliased, barrier-separated):
    //   B1: centroids as float4[32][128], chunk-rotated by 2*(cl>>3)
    //   post-B1 meta: ints [1024..1279]=s_asg, [1280..1535]=s_old,
    //                 floats [1536..1791]=s_inv
    //   B2 sums: i64 [32][128] at float offset 2048 (32 KiB)
    //   C: floats [0..15] = s_red
    __shared__ float s_buf[Kk * Cc];
    int*       s_asg  = (int*)(s_buf + 1024);
    int*       s_old  = (int*)(s_buf + 1280);
    float*     s_inv  = s_buf + 1536;
    long long* s_sums = (long long*)(s_buf + 2048);
    float*     s_red  = s_buf;

    // ---------------- init: inverse norms (4 threads per point) ----------------
    {
        const int gtid = bid * TPB + t;       // 0..262143
        const int p    = gtid >> 2;           // global point id 0..65535
        const int qd   = gtid & 3;
        const float* xr = x + (size_t)p * Cc + qd * 128;
        float ss = 0.f;
        #pragma unroll
        for (int c0 = 0; c0 < 128; c0 += 4) {
            float4 v = *(const float4*)(xr + c0);
            ss = fmaf(v.x, v.x, fmaf(v.y, v.y, fmaf(v.z, v.z, fmaf(v.w, v.w, ss))));
        }
        ss += __shfl_xor(ss, 1);
        ss += __shfl_xor(ss, 2);
        if (qd == 0) invn[p] = 1.0f / fmaxf(sqrtf(ss), 1e-12f);
        // zero persistent accumulators + flags + assignments (ws poisoned 0xAA)
        for (int e = gtid; e < Bb * Kk * Cc; e += GRID * TPB) psums[e] = 0;
        if (gtid < Bb * Kk) pcounts[gtid] = 0;
        if (gtid < ITERS)   flags[gtid] = 0;
        for (int e = gtid; e < Bb * Nn; e += GRID * TPB) assign[e] = -1;
    }
    gg.sync();

    // ---------------- init: gather + normalize initial centroids ----------------
    {
        const int gtid = bid * TPB + t;
        for (int e = gtid; e < Bb * Kk * Cc; e += GRID * TPB) {
            const int c  = e & (Cc - 1);
            const int bk = e >> 9;            // / 512
            const int k  = bk & (Kk - 1);
            const int bb = bk >> 5;           // / 32
            const int pid = idx[bb * Kk + k];
            cent[e] = x[((size_t)bb * Nn + pid) * Cc + c] * invn[bb * Nn + pid];
        }
    }
    gg.sync();

    const float* xb = x + (size_t)b * Nn * Cc;

    for (int it = 0; it < ITERS; ++it) {
        if (it > 0) {
            // No assignment changed last iteration => bit-exact fixed point.
            int ch = __hip_atomic_load(&flags[it - 1], __ATOMIC_RELAXED,
                                       __HIP_MEMORY_SCOPE_AGENT);
            if (ch == 0) break;               // uniform across grid
        }

        // ---- stage centroids into LDS float4[32][128], chunk-rotated ----
        // rot(cl, ch) = (ch + 2*(cl>>3)) & 127 : the 4 cluster-groups land on
        // different bank-slots -> B1 reads are at most 2-way (free).
        {
            const float4* cbp = (const float4*)(cent + (size_t)b * Kk * Cc);
            float4* sb4 = (float4*)s_buf;
            #pragma unroll
            for (int e = t; e < Kk * 128; e += TPB) {        // 4 per thread
                const int cl = e >> 7, ch = e & 127;
                sb4[(cl << 7) | ((ch + 2 * (cl >> 3)) & 127)] = cbp[e];
            }
        }
        __syncthreads();

        // ---- B1: register-blocked 4pt x 8cl x 128ch per thread ----
        // t = pg*16 + cg*4 + qd ; pg=0..63 (4 pts), cg=0..3 (8 cls), qd=0..3
        const int pg = t >> 4;
        const int cg = (t >> 2) & 3;
        const int qd = t & 3;
        const int p0 = pg << 2;
        const float* xr0 = xb + (size_t)(base + p0) * Cc;
        const float4* sb4 = (const float4*)s_buf;
        const int ro   = qd + 2 * cg;         // rotated chunk offset
        const int cbase = cg << 10;           // (cg*8) << 7

        float sim[4][8];
        #pragma unroll
        for (int i = 0; i < 4; ++i)
            #pragma unroll
            for (int l = 0; l < 8; ++l) sim[i][l] = 0.f;

        // software pipeline on the 4 x-frags (chunk j+1 prefetched)
        float4 xf[4];
        #pragma unroll
        for (int i = 0; i < 4; ++i)
            xf[i] = *(const float4*)(xr0 + (size_t)i * Cc + 4 * qd);
        for (int j = 0; j < 32; ++j) {
            float4 xn[4];
            const int chn = (qd + 4 * ((j + 1) & 31)) << 2;  // wrap: reload ch0
            #pragma unroll
            for (int i = 0; i < 4; ++i)
                xn[i] = *(const float4*)(xr0 + (size_t)i * Cc + chn);
            const int lc = (ro + 4 * j) & 127;
            #pragma unroll
            for (int l = 0; l < 8; ++l) {
                const float4 cf = sb4[cbase + (l << 7) + lc]; // 16-lane bcast
                #pragma unroll
                for (int i = 0; i < 4; ++i)
                    sim[i][l] = fmaf(xf[i].x, cf.x,
                                fmaf(xf[i].y, cf.y,
                                fmaf(xf[i].z, cf.z,
                                fmaf(xf[i].w, cf.w, sim[i][l]))));
            }
            #pragma unroll
            for (int i = 0; i < 4; ++i) xf[i] = xn[i];
        }

        // quad reduction over qd (commutative pairs -> identical in all lanes)
        #pragma unroll
        for (int i = 0; i < 4; ++i)
            #pragma unroll
            for (int l = 0; l < 8; ++l) {
                sim[i][l] += __shfl_xor(sim[i][l], 1);
                sim[i][l] += __shfl_xor(sim[i][l], 2);
            }

        // argmax: local over 8 (ascending, strict >), then butterfly over cg
        // with lowest-cluster tie-break (matches reference first-max).
        float bv4[4]; int bi4[4];
        #pragma unroll
        for (int i = 0; i < 4; ++i) {
            float bv = sim[i][0]; int bi = cg * 8;
            #pragma unroll
            for (int l = 1; l < 8; ++l)
                if (sim[i][l] > bv) { bv = sim[i][l]; bi = cg * 8 + l; }
            #pragma unroll
            for (int m = 4; m <= 8; m <<= 1) {
                const float ov = __shfl_xor(bv, m);
                const int   oi = __shfl_xor(bi, m);
                if (ov > bv || (ov == bv && oi < bi)) { bv = ov; bi = oi; }
            }
            bv4[i] = bv; bi4[i] = bi;
        }

        __syncthreads();   // ALL centroid reads done -> s_buf reusable

        if ((t & 15) == 0) {                  // one writer per 4 points
            #pragma unroll
            for (int i = 0; i < 4; ++i) {
                const int n   = base + p0 + i;
                const int bki = bi4[i];
                const int prev = assign[b * Nn + n];
                if (bki != prev) {
                    atomicOr(&flags[it], 1);
                    atomicAdd(&pcounts[b * Kk + bki], 1);
                    if (prev >= 0) atomicAdd(&pcounts[b * Kk + prev], -1);
                    assign[b * Nn + n] = bki;
                }
                s_asg[p0 + i] = bki;
                s_old[p0 + i] = prev;
                s_inv[p0 + i] = invn[b * Nn + n];
            }
        }
        __syncthreads();

        // ---------- B2: delta update of persistent i64 sums, 4 column passes ----
        // Only points whose assignment changed contribute (+q to new, -q to old).
        // Integer adds are exact => delta == full recompute, bit-identical.
        const int col_l = t & 127;
        const int h     = (t >> 7) & 7;      // 8 point-groups of 32 (wave-uniform)
        for (int pass = 0; pass < 4; ++pass) {
            for (int e = t; e < Kk * 128; e += TPB) s_sums[e] = 0;
            __syncthreads();
            const int col = pass * 128 + col_l;
            for (int j = 0; j < 32; ++j) {
                const int p2 = h * 32 + j;                 // uniform per wave
                const int a  = s_asg[p2];                  // LDS broadcast
                const int o  = s_old[p2];
                if (a == o) continue;                      // unchanged: skip
                const float sc = s_inv[p2];
                const float v  = xb[(size_t)(base + p2) * Cc + col]; // coalesced
                const long long q = (long long)(v * sc * SCALE_F);
                atomicAdd((unsigned long long*)&s_sums[a * 128 + col_l],
                          (unsigned long long)q);
                if (o >= 0)
                    atomicAdd((unsigned long long*)&s_sums[o * 128 + col_l],
                              (unsigned long long)(-q));
            }
            __syncthreads();
            for (int e = t; e < Kk * 128; e += TPB) {      // 4 per thread
                const long long q = s_sums[e];
                if (q != 0) {
                    const int k = e >> 7;
                    const int c = (e & 127) + pass * 128;
                    atomicAdd((unsigned long long*)&psums[((size_t)b * Kk + k) * Cc + c],
                              (unsigned long long)q);      // exact integer add
                }
            }
            __syncthreads();
        }
        gg.sync();

        // ---------- C: finalize 2 centroids per block (persistent sums) ----------
        for (int r = 0; r < 2; ++r) {
            const int ci = 2 * bid + r;                    // b*32 + k, 0..511
            float* crow = cent + (size_t)ci * Cc;
            float m = 0.f;
            if (t < Cc) {
                const long long q = psums[(size_t)ci * Cc + t];
                const int cnt = pcounts[ci];               // uniform
                const float s = (float)q * INVSCALE;
                m = (cnt > 0) ? (s / (float)cnt) : crow[t]; // empty: keep old
            }
            float ss = m * m;
            #pragma unroll
            for (int o = 32; o > 0; o >>= 1) ss += __shfl_down(ss, o, 64);
            if ((t & 63) == 0) s_red[t >> 6] = ss;
            __syncthreads();
            float tot = 0.f;
            #pragma unroll
            for (int w = 0; w < TPB / 64; ++w) tot += s_red[w];  // waves>=8 wrote 0
            if (t < Cc) crow[t] = m * (1.0f / fmaxf(sqrtf(tot), 1e-12f));
            __syncthreads();
        }
        gg.sync();
    }

    // ---------------- output ----------------
    {
        const int gtid = bid * TPB + t;
        for (int e = gtid; e < Bb * Kk * Cc; e += GRID * TPB)
            out[e] = cent[e];
    }
}

extern "C" void kernel_launch(void* const* d_in, const int* in_sizes, int n_in,
                              void* d_out, int out_size, void* d_ws, size_t ws_size,
                              hipStream_t stream) {
    const float* x  = (const float*)d_in[0];
    const int* idx  = (const int*)d_in[1];
    float* out      = (float*)d_out;

    // workspace carve-up (~3.5 MiB total; 8-byte-aligned region first)
    char* ws = (char*)d_ws;
    size_t off = 0;
    long long* psums = (long long*)(ws + off); off += (size_t)Bb * Kk * Cc * 8;  // 2 MiB
    float* invn      = (float*)(ws + off);     off += (size_t)Bb * Nn * 4;       // 256 KiB
    float* cent      = (float*)(ws + off);     off += (size_t)Bb * Kk * Cc * 4;  // 1 MiB
    int*   pcounts   = (int*)  (ws + off);     off += (size_t)Bb * Kk * 4;       // 2 KiB
    int*   assign    = (int*)  (ws + off);     off += (size_t)Bb * Nn * 4;       // 256 KiB
    int*   flags     = (int*)  (ws + off);     off += (size_t)ITERS * 4;

    void* args[] = { (void*)&x, (void*)&idx, (void*)&out, (void*)&invn,
                     (void*)&cent, (void*)&psums, (void*)&pcounts,
                     (void*)&assign, (void*)&flags };
    hipLaunchCooperativeKernel((const void*)kmeans_fused, dim3(GRID), dim3(TPB),
                               args, 0, stream);
}